// Round 2
// baseline (29.522 us; speedup 1.0000x reference)
//
#include <hip/hip_runtime.h>
#include <math.h>

// Multi-scale glimpse sensor.
// img: (B, 224, 224, 3) f32, loc: (B, 2) f32 in [-1, 1]
// out: (B, 3, 16, 16, 3) f32
//
// Semantics matched to JAX reference (verified passing R1, absmax 9.8e-4):
//  - cy = clip(floor((loc0+1)*0.5*H), 0, H), cx likewise with W
//  - scale i: patch side d = 16<<i, top-left = (cy - d/2, cx - d/2) in
//    original image coords; out-of-image taps contribute 0 (zero pad).
//  - jax.image.resize bilinear antialias=True: stride s = d/16, T = 2s taps,
//    base weight 1 - |t-(T-1)/2|/s, normalized over taps inside the PATCH
//    [0, d) per axis. d=16 => identity.
//
// R1 -> R2: thread = (jy, jx, ch) (768-thread blocks, 12 waves) so the
// critical scale-2 blocks run 3 waves/SIMD instead of 1, and per-lane tap
// count drops 192 -> 64. X-axis validity folded into precomputed weights
// (clamped offsets), removing the per-tap branch.

#define IMG_H 224
#define IMG_W 224
#define IMG_C 3
#define GW    16
#define KSC   3

template <int STRIDE>
__device__ inline float glimpse_accum_ch(const float* __restrict__ img, int b,
                                         int oy0, int ox0, int jy, int jx,
                                         int ch) {
  constexpr int T = STRIDE * 2;            // taps per axis
  constexpr int D = GW * STRIDE;           // patch side
  constexpr float INV_KS = 1.0f / (float)STRIDE;
  constexpr float CTR = 0.5f * (float)(T - 1);

  const int ky0 = STRIDE * jy - (STRIDE / 2);  // first tap, patch coords
  const int kx0 = STRIDE * jx - (STRIDE / 2);

  float wy[T];
  float wxe[T];     // x weights with patch-bounds AND image-bounds folded in
  int offx[T];      // clamped float-index offset within a row (incl. channel)
  float sy = 0.f, sx = 0.f;
#pragma unroll
  for (int t = 0; t < T; ++t) {
    const float wb = 1.0f - fabsf((float)t - CTR) * INV_KS;
    const int ky = ky0 + t;
    const int kx = kx0 + t;
    const float wyt = (ky >= 0 && ky < D) ? wb : 0.f;
    const float wxt = (kx >= 0 && kx < D) ? wb : 0.f;
    wy[t] = wyt;
    sy += wyt;
    sx += wxt;                              // norm over patch-valid taps only
    const int xx = ox0 + kx;                // original-image col
    const bool xok = (xx >= 0 && xx < IMG_W);
    wxe[t] = xok ? wxt : 0.f;               // image-OOB -> contributes 0
    const int xc = min(max(xx, 0), IMG_W - 1);
    offx[t] = xc * IMG_C + ch;
  }
  const float inv_norm = 1.0f / (sy * sx);

  float a = 0.f;
#pragma unroll
  for (int ty = 0; ty < T; ++ty) {
    const int yy = oy0 + ky0 + ty;          // original-image row
    if (wy[ty] == 0.f || yy < 0 || yy >= IMG_H) continue;
    const float* rowp = img + ((size_t)b * IMG_H + yy) * (IMG_W * IMG_C);
    float r = 0.f;
#pragma unroll
    for (int tx = 0; tx < T; ++tx) {
      r += wxe[tx] * rowp[offx[tx]];        // pure load+FMA inner loop
    }
    a += wy[ty] * r;
  }
  return a * inv_norm;
}

__global__ __launch_bounds__(768) void glimpse_kernel(
    const float* __restrict__ img, const float* __restrict__ loc,
    float* __restrict__ out) {
  const int blk = blockIdx.x;      // b * KSC + scale
  const int b = blk / KSC;
  const int sc = blk % KSC;        // block-uniform => no divergence
  const int tid = threadIdx.x;     // 0..767
  const int ch = tid >> 8;         // 0..2  (wave-uniform)
  const int pix = tid & 255;
  const int jy = pix >> 4;
  const int jx = pix & 15;

  const float ly = loc[b * 2 + 0];
  const float lx = loc[b * 2 + 1];
  int cy = (int)floorf((ly + 1.0f) * 0.5f * (float)IMG_H);
  int cx = (int)floorf((lx + 1.0f) * 0.5f * (float)IMG_W);
  cy = min(max(cy, 0), IMG_H);
  cx = min(max(cx, 0), IMG_W);

  const int d = GW << sc;
  const int half = d >> 1;
  const int oy0 = cy - half;       // patch top-left in original image coords
  const int ox0 = cx - half;

  float acc = 0.f;

  if (sc == 0) {
    // d == 16: resize is identity; just a (possibly zero-padded) gather.
    const int yy = oy0 + jy;
    const int xx = ox0 + jx;
    if (yy >= 0 && yy < IMG_H && xx >= 0 && xx < IMG_W) {
      acc = img[(((size_t)b * IMG_H + yy) * IMG_W + xx) * IMG_C + ch];
    }
  } else if (sc == 1) {
    acc = glimpse_accum_ch<2>(img, b, oy0, ox0, jy, jx, ch);
  } else {
    acc = glimpse_accum_ch<4>(img, b, oy0, ox0, jy, jx, ch);
  }

  // out layout: (B, K, 16, 16, C)
  out[((size_t)blk * 256 + pix) * 3 + ch] = acc;
}

extern "C" void kernel_launch(void* const* d_in, const int* in_sizes, int n_in,
                              void* d_out, int out_size, void* d_ws, size_t ws_size,
                              hipStream_t stream) {
  const float* img = (const float*)d_in[0];
  const float* loc = (const float*)d_in[1];
  float* out = (float*)d_out;
  const int B = in_sizes[1] / 2;   // loc is (B, 2)
  glimpse_kernel<<<B * KSC, 768, 0, stream>>>(img, loc, out);
}

// Round 3
// 14.518 us; speedup vs baseline: 2.0334x; 2.0334x over previous
//
#include <hip/hip_runtime.h>
#include <math.h>

// Multi-scale glimpse sensor.
// img: (B, 224, 224, 3) f32, loc: (B, 2) f32 in [-1, 1]
// out: (B, 3, 16, 16, 3) f32
//
// Semantics matched to JAX reference (verified passing R1, absmax 9.8e-4):
//  - cy = clip(floor((loc0+1)*0.5*H), 0, H), cx likewise
//  - scale i: patch side d = 16<<i, top-left = (cy - d/2, cx - d/2) in
//    original image coords; out-of-image taps contribute 0 (zero pad).
//  - jax.image.resize bilinear antialias=True: stride s = d/16, T = 2s taps,
//    base weight 1 - |t-(T-1)/2|/s, normalized PER AXIS over taps inside the
//    patch [0, d). d=16 => identity.
//
// R2 regressed (29.5us): channel-split killed dwordx3 vectorization (3x VMEM
// instrs). R3: separable two-pass resize. Vertical pass reads global with
// lanes on consecutive columns -> 768B contiguous per tap (coalesced), T taps
// instead of T^2. Horizontal pass reads a channel-planar LDS intermediate with
// row stride 65 (pad breaks the stride-4 bank conflict: 8-way -> 2-way=free).

#define IMG_H 224
#define IMG_W 224
#define IMG_C 3
#define GW    16
#define KSC   3
#define ROWF  (IMG_W * IMG_C)   // floats per image row = 672
#define PLANE 1040              // 16 rows * 65 (padded) per channel plane

template <int S>
__device__ inline void glimpse_scale(const float* __restrict__ img, int b,
                                     int oy0, int ox0, int tid,
                                     float* vsm, float* __restrict__ outp) {
  constexpr int T = 2 * S;                  // taps per axis
  constexpr int D = GW * S;                 // patch side
  constexpr float CTR = 0.5f * (float)(T - 1);

  float wb[T];
#pragma unroll
  for (int t = 0; t < T; ++t)
    wb[t] = 1.0f - fabsf((float)t - CTR) / (float)S;

  // ---- vertical pass: intermediate v(i, x), i in [0,16), x in [0,D) ----
  constexpr int ITERS = (16 * D) / 256;
  const float* imgb = img + (size_t)b * IMG_H * ROWF;
#pragma unroll
  for (int it = 0; it < ITERS; ++it) {
    const int task = tid + it * 256;
    const int x = task & (D - 1);           // lanes -> consecutive columns
    const int i = task / D;
    const int ky0 = S * i - S / 2;          // first tap, patch coords
    const int xx = ox0 + x;                 // original-image column
    float a0 = 0.f, a1 = 0.f, a2 = 0.f;
    if (xx >= 0 && xx < IMG_W) {
      float sy = 0.f;
      const float* colp = imgb + (size_t)xx * IMG_C;
#pragma unroll
      for (int t = 0; t < T; ++t) {
        const int ky = ky0 + t;
        if (ky < 0 || ky >= D) continue;    // patch bounds -> excluded from norm
        sy += wb[t];
        const int yy = oy0 + ky;
        if (yy < 0 || yy >= IMG_H) continue;  // zero-pad region
        const float* p = colp + (size_t)yy * ROWF;   // coalesced dwordx3
        a0 = fmaf(wb[t], p[0], a0);
        a1 = fmaf(wb[t], p[1], a1);
        a2 = fmaf(wb[t], p[2], a2);
      }
      const float rsy = 1.0f / sy;          // per-axis normalization (y)
      a0 *= rsy; a1 *= rsy; a2 *= rsy;
    }
    const int woff = i * 65 + x;            // padded row stride 65
    vsm[0 * PLANE + woff] = a0;
    vsm[1 * PLANE + woff] = a1;
    vsm[2 * PLANE + woff] = a2;
  }
  __syncthreads();

  // ---- horizontal pass: one output pixel per thread ----
  const int jy = tid >> 4;
  const int jx = tid & 15;
  const int kx0 = S * jx - S / 2;
  float sx = 0.f, a0 = 0.f, a1 = 0.f, a2 = 0.f;
#pragma unroll
  for (int t = 0; t < T; ++t) {
    const int kx = kx0 + t;
    if (kx < 0 || kx >= D) continue;        // patch bounds -> excluded
    sx += wb[t];
    const int base = jy * 65 + kx;
    a0 = fmaf(wb[t], vsm[0 * PLANE + base], a0);
    a1 = fmaf(wb[t], vsm[1 * PLANE + base], a1);
    a2 = fmaf(wb[t], vsm[2 * PLANE + base], a2);
  }
  const float rsx = 1.0f / sx;              // per-axis normalization (x)
  float* o = outp + (size_t)tid * 3;
  o[0] = a0 * rsx;
  o[1] = a1 * rsx;
  o[2] = a2 * rsx;
}

__global__ __launch_bounds__(256) void glimpse_kernel(
    const float* __restrict__ img, const float* __restrict__ loc,
    float* __restrict__ out) {
  __shared__ float vsm[3 * PLANE];          // 12.5 KB

  const int blk = blockIdx.x;               // b * KSC + scale
  const int b = blk / KSC;
  const int sc = blk % KSC;                 // block-uniform
  const int tid = threadIdx.x;              // 0..255

  const float ly = loc[b * 2 + 0];
  const float lx = loc[b * 2 + 1];
  int cy = (int)floorf((ly + 1.0f) * 0.5f * (float)IMG_H);
  int cx = (int)floorf((lx + 1.0f) * 0.5f * (float)IMG_W);
  cy = min(max(cy, 0), IMG_H);
  cx = min(max(cx, 0), IMG_W);

  const int d = GW << sc;
  const int half = d >> 1;
  const int oy0 = cy - half;                // patch top-left, image coords
  const int ox0 = cx - half;

  float* outp = out + (size_t)blk * 256 * 3;

  if (sc == 0) {
    // d == 16: identity resize; direct (possibly zero-padded) gather.
    const int jy = tid >> 4;
    const int jx = tid & 15;
    const int yy = oy0 + jy;
    const int xx = ox0 + jx;
    float a0 = 0.f, a1 = 0.f, a2 = 0.f;
    if (yy >= 0 && yy < IMG_H && xx >= 0 && xx < IMG_W) {
      const float* p = img + (((size_t)b * IMG_H + yy) * IMG_W + xx) * IMG_C;
      a0 = p[0]; a1 = p[1]; a2 = p[2];
    }
    float* o = outp + (size_t)tid * 3;
    o[0] = a0; o[1] = a1; o[2] = a2;
  } else if (sc == 1) {
    glimpse_scale<2>(img, b, oy0, ox0, tid, vsm, outp);
  } else {
    glimpse_scale<4>(img, b, oy0, ox0, tid, vsm, outp);
  }
}

extern "C" void kernel_launch(void* const* d_in, const int* in_sizes, int n_in,
                              void* d_out, int out_size, void* d_ws, size_t ws_size,
                              hipStream_t stream) {
  const float* img = (const float*)d_in[0];
  const float* loc = (const float*)d_in[1];
  float* out = (float*)d_out;
  const int B = in_sizes[1] / 2;            // loc is (B, 2)
  glimpse_kernel<<<B * KSC, 256, 0, stream>>>(img, loc, out);
}

// Round 4
// 9.858 us; speedup vs baseline: 2.9946x; 1.4727x over previous
//
#include <hip/hip_runtime.h>
#include <math.h>

// Multi-scale glimpse sensor — fused single-launch version.
// img: (B, 224, 224, 3) f32, loc: (B, 2) f32 in [-1, 1]
// out: (B, 3, 16, 16, 3) f32
//
// Semantics (verified R1/R3, absmax ~2e-4):
//  - cy = clip(floor((loc0+1)*0.5*H), 0, H), cx likewise
//  - scale i: patch side d = 16<<i, top-left (cy-d/2, cx-d/2) in image
//    coords; out-of-image taps contribute 0 (zero pad).
//  - jax.image.resize bilinear antialias=True: s = d/16, T = 2s taps,
//    base weight 1-|t-(T-1)/2|/s, normalized PER AXIS over taps inside
//    the patch [0,d). d=16 => identity.
//
// R3 -> R4: R1 vs R3 moved <1us despite 3x work reduction => fixed
// launch/replay overhead floor hypothesis. This version minimizes kernel
// GPU time structurally: grid = B (1 block/CU, no tail), 512 threads
// (2 waves/SIMD), all 3 scales fused in one block, fully predicated
// clamped loads (no divergence), separable resize with LDS intermediates.

#define IMG_H 224
#define IMG_W 224
#define ROWF  672               // 224*3 floats per image row
#define RS2   193               // v2 row stride (64*3 + 1)
#define RS1   97                // v1 row stride (32*3 + 1)

struct F3 { float x, y, z; };

__device__ __forceinline__ F3 ld3(const float* p) {
  return *(const F3*)p;
}

__global__ __launch_bounds__(512) void glimpse_kernel(
    const float* __restrict__ img, const float* __restrict__ loc,
    float* __restrict__ out) {
  __shared__ float v2[16 * RS2];   // vertical intermediate, scale 2
  __shared__ float v1[16 * RS1];   // vertical intermediate, scale 1

  const int b = blockIdx.x;
  const int tid = threadIdx.x;     // 0..511

  const float ly = loc[b * 2 + 0];
  const float lx = loc[b * 2 + 1];
  int cy = (int)floorf((ly + 1.0f) * 0.5f * (float)IMG_H);
  int cx = (int)floorf((lx + 1.0f) * 0.5f * (float)IMG_W);
  cy = min(max(cy, 0), IMG_H);
  cx = min(max(cx, 0), IMG_W);
  const int oy0 = cy - 32;         // scale-2 patch top-left
  const int ox0 = cx - 32;

  const float* imgb = img + (size_t)b * IMG_H * ROWF;

  // tap base weights
  float wb2[8], wb1[4];
#pragma unroll
  for (int t = 0; t < 8; ++t) wb2[t] = 1.0f - fabsf((float)t - 3.5f) * 0.25f;
#pragma unroll
  for (int t = 0; t < 4; ++t) wb1[t] = 1.0f - fabsf((float)t - 1.5f) * 0.5f;

  // ---- vertical pass, scale 2: v2(i, x), i in [0,16), x in [0,64) ----
#pragma unroll
  for (int it = 0; it < 2; ++it) {
    const int task = it * 512 + tid;
    const int x = task & 63;                 // wave = one full row
    const int i = task >> 6;
    const int ky0 = 4 * i - 2;
    const int xx = ox0 + x;
    const int xc = min(max(xx, 0), IMG_W - 1);
    const float fx = ((unsigned)xx < IMG_W) ? 1.0f : 0.f;
    float a0 = 0.f, a1 = 0.f, a2 = 0.f;
#pragma unroll
    for (int t = 0; t < 8; ++t) {
      const int ky = ky0 + t;
      const int yy = oy0 + ky;
      const float we =
          (((unsigned)ky < 64u) && ((unsigned)yy < IMG_H)) ? wb2[t] * fx : 0.f;
      const int yc = min(max(yy, 0), IMG_H - 1);
      const F3 p = ld3(imgb + (size_t)yc * ROWF + (size_t)xc * 3);
      a0 = fmaf(we, p.x, a0);
      a1 = fmaf(we, p.y, a1);
      a2 = fmaf(we, p.z, a2);
    }
    const float rsy = (i == 0 || i == 15) ? (1.0f / 3.5f) : 0.25f;
    const int w = i * RS2 + 3 * x;
    v2[w + 0] = a0 * rsy;
    v2[w + 1] = a1 * rsy;
    v2[w + 2] = a2 * rsy;
  }

  // ---- vertical pass, scale 1: v1(i, x), x in [0,32); patch offset +16 ----
  {
    const int x = tid & 31;
    const int i = tid >> 5;
    const int ky0 = 2 * i - 1;
    const int xx = ox0 + 16 + x;
    const int xc = min(max(xx, 0), IMG_W - 1);
    const float fx = ((unsigned)xx < IMG_W) ? 1.0f : 0.f;
    float a0 = 0.f, a1 = 0.f, a2 = 0.f;
#pragma unroll
    for (int t = 0; t < 4; ++t) {
      const int ky = ky0 + t;
      const int yy = oy0 + 16 + ky;
      const float we =
          (((unsigned)ky < 32u) && ((unsigned)yy < IMG_H)) ? wb1[t] * fx : 0.f;
      const int yc = min(max(yy, 0), IMG_H - 1);
      const F3 p = ld3(imgb + (size_t)yc * ROWF + (size_t)xc * 3);
      a0 = fmaf(we, p.x, a0);
      a1 = fmaf(we, p.y, a1);
      a2 = fmaf(we, p.z, a2);
    }
    const float rsy = (i == 0 || i == 15) ? (1.0f / 1.75f) : 0.5f;
    const int w = i * RS1 + 3 * x;
    v1[w + 0] = a0 * rsy;
    v1[w + 1] = a1 * rsy;
    v1[w + 2] = a2 * rsy;
  }

  // ---- scale 0: identity gather (global only, no LDS dependency) ----
  if (tid < 256) {
    const int jy = tid >> 4;
    const int jx = tid & 15;
    const int yy = oy0 + 24 + jy;
    const int xx = ox0 + 24 + jx;
    const float we =
        (((unsigned)yy < IMG_H) && ((unsigned)xx < IMG_W)) ? 1.0f : 0.f;
    const int yc = min(max(yy, 0), IMG_H - 1);
    const int xc = min(max(xx, 0), IMG_W - 1);
    const F3 p = ld3(imgb + (size_t)yc * ROWF + (size_t)xc * 3);
    float* o = out + ((size_t)(b * 3 + 0) * 256 + tid) * 3;
    o[0] = we * p.x;
    o[1] = we * p.y;
    o[2] = we * p.z;
  }

  __syncthreads();

  // ---- horizontal pass + store: waves 0-3 scale 2, waves 4-7 scale 1 ----
  if (tid < 256) {
    const int jy = tid >> 4;
    const int jx = tid & 15;
    const int kx0 = 4 * jx - 2;
    float a0 = 0.f, a1 = 0.f, a2 = 0.f;
#pragma unroll
    for (int t = 0; t < 8; ++t) {
      const int kx = kx0 + t;
      const float we = ((unsigned)kx < 64u) ? wb2[t] : 0.f;
      const int kc = min(max(kx, 0), 63);
      const int base = jy * RS2 + 3 * kc;
      a0 = fmaf(we, v2[base + 0], a0);
      a1 = fmaf(we, v2[base + 1], a1);
      a2 = fmaf(we, v2[base + 2], a2);
    }
    const float rsx = (jx == 0 || jx == 15) ? (1.0f / 3.5f) : 0.25f;
    float* o = out + ((size_t)(b * 3 + 2) * 256 + tid) * 3;
    o[0] = a0 * rsx;
    o[1] = a1 * rsx;
    o[2] = a2 * rsx;
  } else {
    const int px = tid - 256;
    const int jy = px >> 4;
    const int jx = px & 15;
    const int kx0 = 2 * jx - 1;
    float a0 = 0.f, a1 = 0.f, a2 = 0.f;
#pragma unroll
    for (int t = 0; t < 4; ++t) {
      const int kx = kx0 + t;
      const float we = ((unsigned)kx < 32u) ? wb1[t] : 0.f;
      const int kc = min(max(kx, 0), 31);
      const int base = jy * RS1 + 3 * kc;
      a0 = fmaf(we, v1[base + 0], a0);
      a1 = fmaf(we, v1[base + 1], a1);
      a2 = fmaf(we, v1[base + 2], a2);
    }
    const float rsx = (jx == 0 || jx == 15) ? (1.0f / 1.75f) : 0.5f;
    float* o = out + ((size_t)(b * 3 + 1) * 256 + px) * 3;
    o[0] = a0 * rsx;
    o[1] = a1 * rsx;
    o[2] = a2 * rsx;
  }
}

extern "C" void kernel_launch(void* const* d_in, const int* in_sizes, int n_in,
                              void* d_out, int out_size, void* d_ws, size_t ws_size,
                              hipStream_t stream) {
  const float* img = (const float*)d_in[0];
  const float* loc = (const float*)d_in[1];
  float* out = (float*)d_out;
  const int B = in_sizes[1] / 2;   // loc is (B, 2)
  glimpse_kernel<<<B, 512, 0, stream>>>(img, loc, out);
}